// Round 1
// baseline (85.768 us; speedup 1.0000x reference)
//
#include <hip/hip_runtime.h>

#define NPE   512
#define KNN   6
#define F_IN  128
#define HDIM  16
#define ODIM  10

typedef __attribute__((ext_vector_type(8))) short short8;
typedef __attribute__((ext_vector_type(4))) float f32x4;

static __device__ __forceinline__ short f2bf(float f) {
  unsigned u = __builtin_bit_cast(unsigned, f);
  u = (u + 0x7fffu + ((u >> 16) & 1u)) >> 16;   // RNE truncate to bf16
  return (short)u;
}
static __device__ __forceinline__ float bflo(unsigned d) {
  return __builtin_bit_cast(float, d << 16);
}
static __device__ __forceinline__ float bfhi(unsigned d) {
  return __builtin_bit_cast(float, d & 0xffff0000u);
}
static __device__ __forceinline__ unsigned umin2(unsigned a, unsigned b) { return a < b ? a : b; }
static __device__ __forceinline__ unsigned umax2(unsigned a, unsigned b) { return a > b ? a : b; }

__global__ __launch_bounds__(512, 4) void gnet_fused(
    const int* __restrict__ coo, const float* __restrict__ x,
    const float* __restrict__ W1, const float* __restrict__ b1,
    const float* __restrict__ W2, const float* __restrict__ b2,
    float* __restrict__ out)
{
  __shared__ __align__(16) unsigned pos_s[NPE];      //  2 KB  x | y<<16
  __shared__ __align__(16) short    h1_s[NPE][24];   // 24 KB  bf16, padded
  __shared__ __align__(16) short    r_s [NPE][24];   // 24 KB  bf16, padded
  __shared__ __align__(16) float    h2_s[NPE][12];   // 24 KB  f32,  padded

  const int tid   = threadIdx.x;
  const int gbase = blockIdx.x * NPE;

  const int cx = coo[(gbase + tid) * 3 + 0];
  const int cy = coo[(gbase + tid) * 3 + 1];
  pos_s[tid] = (unsigned)cx | ((unsigned)cy << 16);
  __syncthreads();

  // ---------------- Phase A: brute-force knn, key = (d2<<9)|j, keep 6 smallest
  unsigned k0 = 0x7fffffffu, k1 = k0, k2 = k0, k3 = k0, k4 = k0, k5 = k0;
  for (int jc = 0; jc < NPE; jc += 4) {
    const uint4 pk = *reinterpret_cast<const uint4*>(&pos_s[jc]);
    const unsigned pv[4] = {pk.x, pk.y, pk.z, pk.w};
#pragma unroll
    for (int q = 0; q < 4; ++q) {
      const int j = jc + q;
      const unsigned p = pv[q];
      const int dx = cx - (int)(p & 0xffffu);
      const int dy = cy - (int)(p >> 16);
      const unsigned d = (unsigned)(__mul24(dx, dx) + __mul24(dy, dy));
      unsigned key = (d << 9) | (unsigned)j;
      if (j == tid) key = 0x7fffffffu;        // exclude self
      if (key < k5) {                          // insert into sorted k0..k5
        k5 = key;
        unsigned lo, hi;
        lo = umin2(k4, k5); hi = umax2(k4, k5); k4 = lo; k5 = hi;
        lo = umin2(k3, k4); hi = umax2(k3, k4); k3 = lo; k4 = hi;
        lo = umin2(k2, k3); hi = umax2(k2, k3); k2 = lo; k3 = hi;
        lo = umin2(k1, k2); hi = umax2(k1, k2); k1 = lo; k2 = hi;
        lo = umin2(k0, k1); hi = umax2(k0, k1); k0 = lo; k1 = hi;
      }
    }
  }
  const int nb0 = (int)(k0 & 511u), nb1 = (int)(k1 & 511u), nb2 = (int)(k2 & 511u);
  const int nb3 = (int)(k3 & 511u), nb4 = (int)(k4 & 511u), nb5 = (int)(k5 & 511u);

  // ---------------- Phase B: h1 = x @ W1 via bf16 MFMA 16x16x32, K=128
  const int ln   = tid & 63;
  const int wv   = tid >> 6;
  const int lcol = ln & 15;   // A-row / B-col / C-col
  const int lkg  = ln >> 4;   // k-group

  short8 bw1[4];
#pragma unroll
  for (int s = 0; s < 4; ++s) {
#pragma unroll
    for (int e = 0; e < 8; ++e) {
      const int k = s * 32 + lkg * 8 + e;
      bw1[s][e] = f2bf(W1[k * HDIM + lcol]);
    }
  }

#pragma unroll
  for (int t = 0; t < 4; ++t) {
    const int nt = wv * 64 + t * 16;
    f32x4 acc = {0.f, 0.f, 0.f, 0.f};
#pragma unroll
    for (int s = 0; s < 4; ++s) {
      const float* xp = x + (size_t)(gbase + nt + lcol) * F_IN + s * 32 + lkg * 8;
      const float4 xa = *reinterpret_cast<const float4*>(xp);
      const float4 xb = *reinterpret_cast<const float4*>(xp + 4);
      short8 af;
      af[0] = f2bf(xa.x); af[1] = f2bf(xa.y); af[2] = f2bf(xa.z); af[3] = f2bf(xa.w);
      af[4] = f2bf(xb.x); af[5] = f2bf(xb.y); af[6] = f2bf(xb.z); af[7] = f2bf(xb.w);
      acc = __builtin_amdgcn_mfma_f32_16x16x32_bf16(af, bw1[s], acc, 0, 0, 0);
    }
#pragma unroll
    for (int i = 0; i < 4; ++i) {
      h1_s[nt + lkg * 4 + i][lcol] = f2bf(acc[i]);   // C: col=lane&15, row=(lane>>4)*4+i
    }
  }
  __syncthreads();

  // ---------------- Phase C: agg1 = (self + 6 nbrs)/7 + b1, ReLU -> r_s (bf16)
  {
    float acc[HDIM];
#pragma unroll
    for (int o = 0; o < HDIM; ++o) acc[o] = 0.f;
    const int rows[7] = {tid, nb0, nb1, nb2, nb3, nb4, nb5};
#pragma unroll
    for (int r = 0; r < 7; ++r) {
      const unsigned* hp = reinterpret_cast<const unsigned*>(h1_s[rows[r]]);
      const uint4 ha = *reinterpret_cast<const uint4*>(hp);
      const uint4 hb = *reinterpret_cast<const uint4*>(hp + 4);
      const unsigned hd[8] = {ha.x, ha.y, ha.z, ha.w, hb.x, hb.y, hb.z, hb.w};
#pragma unroll
      for (int q = 0; q < 8; ++q) {
        acc[2 * q]     += bflo(hd[q]);
        acc[2 * q + 1] += bfhi(hd[q]);
      }
    }
    const float inv = 1.0f / 7.0f;
    unsigned* rp = reinterpret_cast<unsigned*>(r_s[tid]);
#pragma unroll
    for (int q = 0; q < 8; ++q) {
      const float v0 = fmaxf(acc[2 * q]     * inv + b1[2 * q],     0.f);
      const float v1 = fmaxf(acc[2 * q + 1] * inv + b1[2 * q + 1], 0.f);
      rp[q] = (unsigned)(unsigned short)f2bf(v0) |
              ((unsigned)(unsigned short)f2bf(v1) << 16);
    }
  }
  __syncthreads();

  // ---------------- Phase D: h2 = r @ W2 via MFMA (K=16 zero-padded to 32)
  short8 bw2 = {0, 0, 0, 0, 0, 0, 0, 0};
  if (lkg < 2 && lcol < ODIM) {
#pragma unroll
    for (int e = 0; e < 8; ++e) {
      const int k = lkg * 8 + e;
      bw2[e] = f2bf(W2[k * ODIM + lcol]);
    }
  }
#pragma unroll
  for (int t = 0; t < 4; ++t) {
    const int nt = wv * 64 + t * 16;
    short8 af = {0, 0, 0, 0, 0, 0, 0, 0};
    if (lkg < 2) {
      af = *reinterpret_cast<const short8*>(&r_s[nt + lcol][lkg * 8]);
    }
    f32x4 acc = {0.f, 0.f, 0.f, 0.f};
    acc = __builtin_amdgcn_mfma_f32_16x16x32_bf16(af, bw2, acc, 0, 0, 0);
#pragma unroll
    for (int i = 0; i < 4; ++i) {
      if (lcol < ODIM) h2_s[nt + lkg * 4 + i][lcol] = acc[i];
    }
  }
  __syncthreads();

  // ---------------- Phase E: agg2 = (self + 6 nbrs)/7 + b2 -> out (f32)
  {
    float acc[ODIM];
#pragma unroll
    for (int c = 0; c < ODIM; ++c) acc[c] = 0.f;
    const int rows[7] = {tid, nb0, nb1, nb2, nb3, nb4, nb5};
#pragma unroll
    for (int r = 0; r < 7; ++r) {
      const float* hp = h2_s[rows[r]];
#pragma unroll
      for (int c = 0; c < ODIM; ++c) acc[c] += hp[c];
    }
    const float inv = 1.0f / 7.0f;
    float* op = out + (size_t)(gbase + tid) * ODIM;
#pragma unroll
    for (int c = 0; c < ODIM; ++c) op[c] = acc[c] * inv + b2[c];
  }
}

extern "C" void kernel_launch(void* const* d_in, const int* in_sizes, int n_in,
                              void* d_out, int out_size, void* d_ws, size_t ws_size,
                              hipStream_t stream) {
  const int*   coo = (const int*)  d_in[0];
  const float* x   = (const float*)d_in[1];
  const float* W1  = (const float*)d_in[2];
  const float* b1  = (const float*)d_in[3];
  const float* W2  = (const float*)d_in[4];
  const float* b2  = (const float*)d_in[5];
  gnet_fused<<<dim3(512), dim3(512), 0, stream>>>(coo, x, W1, b1, W2, b2,
                                                  (float*)d_out);
}

// Round 2
// 41.286 us; speedup vs baseline: 2.0774x; 2.0774x over previous
//
#include <hip/hip_runtime.h>

#define NPE   512
#define F_IN  128
#define HDIM  16
#define ODIM  10

typedef __attribute__((ext_vector_type(8))) short short8;
typedef __attribute__((ext_vector_type(4))) float f32x4;

static __device__ __forceinline__ short f2bf(float f) {
  unsigned u = __builtin_bit_cast(unsigned, f);
  u = (u + 0x7fffu + ((u >> 16) & 1u)) >> 16;   // RNE truncate to bf16
  return (short)u;
}
static __device__ __forceinline__ float bflo(unsigned d) {
  return __builtin_bit_cast(float, d << 16);
}
static __device__ __forceinline__ float bfhi(unsigned d) {
  return __builtin_bit_cast(float, d & 0xffff0000u);
}
static __device__ __forceinline__ unsigned umin2(unsigned a, unsigned b) { return a < b ? a : b; }
static __device__ __forceinline__ unsigned umax2(unsigned a, unsigned b) { return a > b ? a : b; }

__global__ __launch_bounds__(512, 4) void gnet_fused(
    const int* __restrict__ coo, const float* __restrict__ x,
    const float* __restrict__ W1, const float* __restrict__ b1,
    const float* __restrict__ W2, const float* __restrict__ b2,
    float* __restrict__ out)
{
  __shared__ __align__(16) short    h1_s[NPE][24];   // 24 KB  bf16, padded
  __shared__ __align__(16) short    r_s [NPE][24];   // 24 KB  bf16, padded
  __shared__ __align__(16) float    h2_s[NPE][12];   // 24 KB  f32,  padded
  __shared__ unsigned       cnt_s [256];             //  1 KB  per-cell count
  __shared__ unsigned       scan_s[256];             //  1 KB  inclusive scan
  __shared__ unsigned       cur_s [256];             //  1 KB  scatter cursor
  __shared__ unsigned short bucket_s[NPE];           //  1 KB  node idx by cell

  const int tid   = threadIdx.x;
  const int gbase = blockIdx.x * NPE;
  const int ln    = tid & 63;
  const int wv    = tid >> 6;
  const int lcol  = ln & 15;
  const int lkg   = ln >> 4;

  const int cx = coo[(gbase + tid) * 3 + 0];
  const int cy = coo[(gbase + tid) * 3 + 1];
  const int mycell = cy * 16 + cx;

  // ---------------- Phase A0: counting-sort nodes into 256 cell buckets
  if (tid < 256) cnt_s[tid] = 0;
  __syncthreads();
  atomicAdd(&cnt_s[mycell], 1u);
  __syncthreads();
  if (tid < 256) scan_s[tid] = cnt_s[tid];
  __syncthreads();
  for (int off = 1; off < 256; off <<= 1) {   // Hillis-Steele inclusive scan
    unsigned v = 0;
    if (tid < 256) { v = scan_s[tid]; if (tid >= off) v += scan_s[tid - off]; }
    __syncthreads();
    if (tid < 256) scan_s[tid] = v;
    __syncthreads();
  }
  if (tid < 256) cur_s[tid] = scan_s[tid] - cnt_s[tid];  // exclusive start
  __syncthreads();
  {
    const unsigned slot = atomicAdd(&cur_s[mycell], 1u);
    bucket_s[slot] = (unsigned short)tid;
  }
  __syncthreads();

  // ---------------- knn via expanding rings over cells (exact, key=(d2<<9)|j)
  unsigned k0 = 0x7fffffffu, k1 = k0, k2 = k0, k3 = k0, k4 = k0, k5 = k0;
  auto insert6 = [&](unsigned key) {
    if (key < k5) {
      k5 = key;
      unsigned lo, hi;
      lo = umin2(k4, k5); hi = umax2(k4, k5); k4 = lo; k5 = hi;
      lo = umin2(k3, k4); hi = umax2(k3, k4); k3 = lo; k4 = hi;
      lo = umin2(k2, k3); hi = umax2(k2, k3); k2 = lo; k3 = hi;
      lo = umin2(k1, k2); hi = umax2(k1, k2); k1 = lo; k2 = hi;
      lo = umin2(k0, k1); hi = umax2(k0, k1); k0 = lo; k1 = hi;
    }
  };
  auto scan_cell = [&](int c, unsigned kb) {
    const unsigned e = scan_s[c];
    const unsigned n = cnt_s[c];
    for (unsigned q = e - n; q < e; ++q) {
      insert6(kb | (unsigned)bucket_s[q]);
    }
  };
  auto knn_scan = [&]() {
    { // own cell: d2 = 0, exclude self
      const unsigned e = scan_s[mycell];
      const unsigned n = cnt_s[mycell];
      for (unsigned q = e - n; q < e; ++q) {
        const unsigned idx = bucket_s[q];
        if ((int)idx == tid) continue;
        insert6(idx);
      }
    }
    for (int r = 1; r <= 15; ++r) {
      const unsigned r2 = (unsigned)(r * r);
      if (r2 > (k5 >> 9)) break;           // remaining keys strictly greater
      // rows dy = ±r, dx = -r..r
      for (int sg = 0; sg < 2; ++sg) {
        const int yy = cy + (sg ? r : -r);
        if (yy < 0 || yy > 15) continue;
        const int xlo = cx - r < 0 ? 0 : cx - r;
        const int xhi = cx + r > 15 ? 15 : cx + r;
        for (int xx = xlo; xx <= xhi; ++xx) {
          const int dx = xx - cx;
          const unsigned kb = (unsigned)(dx * dx + (int)r2) << 9;
          if (kb < k5) scan_cell(yy * 16 + xx, kb);
        }
      }
      // cols dx = ±r, dy = -r+1..r-1
      for (int sg = 0; sg < 2; ++sg) {
        const int xx = cx + (sg ? r : -r);
        if (xx < 0 || xx > 15) continue;
        const int ylo = cy - r + 1 < 0 ? 0 : cy - r + 1;
        const int yhi = cy + r - 1 > 15 ? 15 : cy + r - 1;
        for (int yy = ylo; yy <= yhi; ++yy) {
          const int dy = yy - cy;
          const unsigned kb = (unsigned)(dy * dy + (int)r2) << 9;
          if (kb < k5) scan_cell(yy * 16 + xx, kb);
        }
      }
    }
  };

  // ---------------- GEMM1: h1 = bf16(x) @ bf16(W1), MFMA 16x16x32, K=128
  auto gemm1 = [&]() {
    short8 bw1[4];
#pragma unroll
    for (int s = 0; s < 4; ++s) {
#pragma unroll
      for (int e = 0; e < 8; ++e) {
        const int k = s * 32 + lkg * 8 + e;
        bw1[s][e] = f2bf(W1[k * HDIM + lcol]);
      }
    }
#pragma unroll
    for (int t = 0; t < 4; ++t) {
      const int nt = wv * 64 + t * 16;
      f32x4 acc = {0.f, 0.f, 0.f, 0.f};
#pragma unroll
      for (int s = 0; s < 4; ++s) {
        const float* xp = x + (size_t)(gbase + nt + lcol) * F_IN + s * 32 + lkg * 8;
        const float4 xa = *reinterpret_cast<const float4*>(xp);
        const float4 xb = *reinterpret_cast<const float4*>(xp + 4);
        short8 af;
        af[0] = f2bf(xa.x); af[1] = f2bf(xa.y); af[2] = f2bf(xa.z); af[3] = f2bf(xa.w);
        af[4] = f2bf(xb.x); af[5] = f2bf(xb.y); af[6] = f2bf(xb.z); af[7] = f2bf(xb.w);
        acc = __builtin_amdgcn_mfma_f32_16x16x32_bf16(af, bw1[s], acc, 0, 0, 0);
      }
#pragma unroll
      for (int i = 0; i < 4; ++i) {
        h1_s[nt + lkg * 4 + i][lcol] = f2bf(acc[i]);  // C: col=lane&15, row=(lane>>4)*4+i
      }
    }
  };

  // Stagger: half the waves do VALU (knn) while the other half stream x (gemm1)
  if (wv & 1) { knn_scan(); gemm1(); }
  else        { gemm1();    knn_scan(); }
  __syncthreads();

  const int nb0 = (int)(k0 & 511u), nb1 = (int)(k1 & 511u), nb2 = (int)(k2 & 511u);
  const int nb3 = (int)(k3 & 511u), nb4 = (int)(k4 & 511u), nb5 = (int)(k5 & 511u);

  // ---------------- Phase C: agg1 = (self + 6 nbrs)/7 + b1, ReLU -> r_s (bf16)
  {
    float acc[HDIM];
#pragma unroll
    for (int o = 0; o < HDIM; ++o) acc[o] = 0.f;
    const int rows[7] = {tid, nb0, nb1, nb2, nb3, nb4, nb5};
#pragma unroll
    for (int r = 0; r < 7; ++r) {
      const unsigned* hp = reinterpret_cast<const unsigned*>(h1_s[rows[r]]);
      const uint4 ha = *reinterpret_cast<const uint4*>(hp);
      const uint4 hb = *reinterpret_cast<const uint4*>(hp + 4);
      const unsigned hd[8] = {ha.x, ha.y, ha.z, ha.w, hb.x, hb.y, hb.z, hb.w};
#pragma unroll
      for (int q = 0; q < 8; ++q) {
        acc[2 * q]     += bflo(hd[q]);
        acc[2 * q + 1] += bfhi(hd[q]);
      }
    }
    const float inv = 1.0f / 7.0f;
    unsigned* rp = reinterpret_cast<unsigned*>(r_s[tid]);
#pragma unroll
    for (int q = 0; q < 8; ++q) {
      const float v0 = fmaxf(acc[2 * q]     * inv + b1[2 * q],     0.f);
      const float v1 = fmaxf(acc[2 * q + 1] * inv + b1[2 * q + 1], 0.f);
      rp[q] = (unsigned)(unsigned short)f2bf(v0) |
              ((unsigned)(unsigned short)f2bf(v1) << 16);
    }
  }
  __syncthreads();

  // ---------------- Phase D: h2 = r @ W2 via MFMA (K=16 zero-padded to 32)
  short8 bw2 = {0, 0, 0, 0, 0, 0, 0, 0};
  if (lkg < 2 && lcol < ODIM) {
#pragma unroll
    for (int e = 0; e < 8; ++e) {
      const int k = lkg * 8 + e;
      bw2[e] = f2bf(W2[k * ODIM + lcol]);
    }
  }
#pragma unroll
  for (int t = 0; t < 4; ++t) {
    const int nt = wv * 64 + t * 16;
    short8 af = {0, 0, 0, 0, 0, 0, 0, 0};
    if (lkg < 2) {
      af = *reinterpret_cast<const short8*>(&r_s[nt + lcol][lkg * 8]);
    }
    f32x4 acc = {0.f, 0.f, 0.f, 0.f};
    acc = __builtin_amdgcn_mfma_f32_16x16x32_bf16(af, bw2, acc, 0, 0, 0);
#pragma unroll
    for (int i = 0; i < 4; ++i) {
      if (lcol < ODIM) h2_s[nt + lkg * 4 + i][lcol] = acc[i];
    }
  }
  __syncthreads();

  // ---------------- Phase E: agg2 = (self + 6 nbrs)/7 + b2 -> out (f32)
  {
    float acc[ODIM];
#pragma unroll
    for (int c = 0; c < ODIM; ++c) acc[c] = 0.f;
    const int rows[7] = {tid, nb0, nb1, nb2, nb3, nb4, nb5};
#pragma unroll
    for (int r = 0; r < 7; ++r) {
      const float* hp = h2_s[rows[r]];
#pragma unroll
      for (int c = 0; c < ODIM; ++c) acc[c] += hp[c];
    }
    const float inv = 1.0f / 7.0f;
    float* op = out + (size_t)(gbase + tid) * ODIM;
#pragma unroll
    for (int c = 0; c < ODIM; ++c) op[c] = acc[c] * inv + b2[c];
  }
}

extern "C" void kernel_launch(void* const* d_in, const int* in_sizes, int n_in,
                              void* d_out, int out_size, void* d_ws, size_t ws_size,
                              hipStream_t stream) {
  const int*   coo = (const int*)  d_in[0];
  const float* x   = (const float*)d_in[1];
  const float* W1  = (const float*)d_in[2];
  const float* b1  = (const float*)d_in[3];
  const float* W2  = (const float*)d_in[4];
  const float* b2  = (const float*)d_in[5];
  gnet_fused<<<dim3(512), dim3(512), 0, stream>>>(coo, x, W1, b1, W2, b2,
                                                  (float*)d_out);
}

// Round 3
// 34.301 us; speedup vs baseline: 2.5004x; 1.2036x over previous
//
#include <hip/hip_runtime.h>

#define NPE   512
#define F_IN  128
#define HDIM  16
#define ODIM  10

typedef __attribute__((ext_vector_type(8))) short short8;
typedef __attribute__((ext_vector_type(4))) float f32x4;

static __device__ __forceinline__ short f2bf(float f) {
  unsigned u = __builtin_bit_cast(unsigned, f);
  u = (u + 0x7fffu + ((u >> 16) & 1u)) >> 16;   // RNE truncate to bf16
  return (short)u;
}
static __device__ __forceinline__ float bflo(unsigned d) {
  return __builtin_bit_cast(float, d << 16);
}
static __device__ __forceinline__ float bfhi(unsigned d) {
  return __builtin_bit_cast(float, d & 0xffff0000u);
}
static __device__ __forceinline__ unsigned umin2(unsigned a, unsigned b) { return a < b ? a : b; }
static __device__ __forceinline__ unsigned umax2(unsigned a, unsigned b) { return a > b ? a : b; }

__global__ __launch_bounds__(512, 4) void gnet_fused(
    const int* __restrict__ coo, const float* __restrict__ x,
    const float* __restrict__ W1, const float* __restrict__ b1,
    const float* __restrict__ W2, const float* __restrict__ b2,
    float* __restrict__ out)
{
  __shared__ __align__(16) short    hbuf[NPE][24];  // 24 KB: h1 (bf16) then h2 (f32[12]) alias
  __shared__ __align__(16) short    r_s [NPE][24];  // 24 KB: relu(agg1) bf16
  __shared__ unsigned       cnt_s [256];
  __shared__ unsigned       scan_s[256];
  __shared__ unsigned       cur_s [256];
  __shared__ unsigned       wtot_s[4];
  __shared__ unsigned short bucket_s[NPE];
  __shared__ unsigned       top7_s[256][8];         // 8 KB: per-cell 7 smallest keys
  __shared__ unsigned       tile_c;

  const int tid   = threadIdx.x;
  const int gbase = blockIdx.x * NPE;
  const int ln    = tid & 63;
  const int wv    = tid >> 6;
  const int lcol  = ln & 15;
  const int lkg   = ln >> 4;

  const int cx = coo[(gbase + tid) * 3 + 0];
  const int cy = coo[(gbase + tid) * 3 + 1];
  const int mycell = cy * 16 + cx;

  // ---------------- A0: counting-sort nodes into 256 cell buckets (shfl scan)
  if (tid < 256) cnt_s[tid] = 0;
  if (tid == 0)  tile_c = 0;
  __syncthreads();
  atomicAdd(&cnt_s[mycell], 1u);
  __syncthreads();
  unsigned sv = 0;
  if (tid < 256) {
    sv = cnt_s[tid];
#pragma unroll
    for (int off = 1; off < 64; off <<= 1) {        // intra-wave inclusive scan
      unsigned u = __shfl_up(sv, off, 64);
      if (ln >= off) sv += u;
    }
    if (ln == 63) wtot_s[wv] = sv;
  }
  __syncthreads();
  if (tid < 256) {
    unsigned add = 0;
#pragma unroll
    for (int w = 0; w < 3; ++w) if (w < wv) add += wtot_s[w];
    sv += add;
    scan_s[tid] = sv;                // inclusive
    cur_s[tid]  = sv - cnt_s[tid];   // exclusive start (scatter cursor)
  }
  __syncthreads();
  {
    const unsigned slot = atomicAdd(&cur_s[mycell], 1u);
    bucket_s[slot] = (unsigned short)tid;
  }
  __syncthreads();

  // W1 fragments (every thread; used in work-steal gemm1)
  short8 bw1[4];
#pragma unroll
  for (int s = 0; s < 4; ++s) {
#pragma unroll
    for (int e = 0; e < 8; ++e) {
      const int k = s * 32 + lkg * 8 + e;
      bw1[s][e] = f2bf(W1[k * HDIM + lcol]);
    }
  }

  // ---------------- cell-level knn: waves 0-3, one cell per thread.
  // Per-cell top-7 smallest keys (key=(d2<<9)|j, d2 cell-to-cell) contains
  // every member node's top-6-excluding-self (self appears at most once).
  if (tid < 256 && cnt_s[tid] != 0) {
    const int ccx = tid & 15, ccy = tid >> 4;
    unsigned k0 = 0x7fffffffu, k1 = k0, k2 = k0, k3 = k0, k4 = k0, k5 = k0, k6 = k0;
    auto insert7 = [&](unsigned key) {
      if (key < k6) {
        k6 = key;
        unsigned lo, hi;
        lo = umin2(k5, k6); hi = umax2(k5, k6); k5 = lo; k6 = hi;
        lo = umin2(k4, k5); hi = umax2(k4, k5); k4 = lo; k5 = hi;
        lo = umin2(k3, k4); hi = umax2(k3, k4); k3 = lo; k4 = hi;
        lo = umin2(k2, k3); hi = umax2(k2, k3); k2 = lo; k3 = hi;
        lo = umin2(k1, k2); hi = umax2(k1, k2); k1 = lo; k2 = hi;
        lo = umin2(k0, k1); hi = umax2(k0, k1); k0 = lo; k1 = hi;
      }
    };
    auto scan_cell = [&](int c, unsigned kb) {
      const unsigned e = scan_s[c];
      const unsigned n = cnt_s[c];
      for (unsigned q = e - n; q < e; ++q) insert7(kb | (unsigned)bucket_s[q]);
    };
    scan_cell(tid, 0u);                             // own cell, d2 = 0
    for (int r = 1; r <= 15; ++r) {
      const unsigned r2 = (unsigned)(r * r);
      if (r2 > (k6 >> 9)) break;                    // all remaining keys > k6
      for (int sg = 0; sg < 2; ++sg) {              // rows dy = ±r
        const int yy = ccy + (sg ? r : -r);
        if (yy < 0 || yy > 15) continue;
        const int xlo = ccx - r < 0 ? 0 : ccx - r;
        const int xhi = ccx + r > 15 ? 15 : ccx + r;
        for (int xx = xlo; xx <= xhi; ++xx) {
          const int dx = xx - ccx;
          const unsigned kb = (unsigned)(dx * dx + (int)r2) << 9;
          if (kb < k6) scan_cell(yy * 16 + xx, kb);
        }
      }
      for (int sg = 0; sg < 2; ++sg) {              // cols dx = ±r
        const int xx = ccx + (sg ? r : -r);
        if (xx < 0 || xx > 15) continue;
        const int ylo = ccy - r + 1 < 0 ? 0 : ccy - r + 1;
        const int yhi = ccy + r - 1 > 15 ? 15 : ccy + r - 1;
        for (int yy = ylo; yy <= yhi; ++yy) {
          const int dy = yy - ccy;
          const unsigned kb = (unsigned)(dy * dy + (int)r2) << 9;
          if (kb < k6) scan_cell(yy * 16 + xx, kb);
        }
      }
    }
    unsigned* tp = top7_s[tid];
    tp[0] = k0; tp[1] = k1; tp[2] = k2; tp[3] = k3; tp[4] = k4; tp[5] = k5; tp[6] = k6;
  }

  // ---------------- gemm1 work-steal: 32 tiles x 16 rows, h1 = bf16(x)@bf16(W1)
  for (;;) {
    int t = 0;
    if (ln == 0) t = (int)atomicAdd(&tile_c, 1u);
    t = __shfl(t, 0, 64);
    if (t >= 32) break;
    const int nt = t * 16;
    f32x4 acc = {0.f, 0.f, 0.f, 0.f};
#pragma unroll
    for (int s = 0; s < 4; ++s) {
      const float* xp = x + (size_t)(gbase + nt + lcol) * F_IN + s * 32 + lkg * 8;
      const float4 xa = *reinterpret_cast<const float4*>(xp);
      const float4 xb = *reinterpret_cast<const float4*>(xp + 4);
      short8 af;
      af[0] = f2bf(xa.x); af[1] = f2bf(xa.y); af[2] = f2bf(xa.z); af[3] = f2bf(xa.w);
      af[4] = f2bf(xb.x); af[5] = f2bf(xb.y); af[6] = f2bf(xb.z); af[7] = f2bf(xb.w);
      acc = __builtin_amdgcn_mfma_f32_16x16x32_bf16(af, bw1[s], acc, 0, 0, 0);
    }
#pragma unroll
    for (int i = 0; i < 4; ++i) {
      hbuf[nt + lkg * 4 + i][lcol] = f2bf(acc[i]);  // C: col=lane&15, row=(lane>>4)*4+i
    }
  }
  __syncthreads();

  // ---------------- per-node neighbors from cell top-7 (branch-free self skip)
  const unsigned* tp = top7_s[mycell];
  const unsigned t0 = tp[0], t1 = tp[1], t2 = tp[2], t3 = tp[3];
  const unsigned t4 = tp[4], t5 = tp[5], t6 = tp[6];
  const unsigned selfkey = (unsigned)tid;           // self key: d2=0 -> key = tid
  int p = 7;
  p = (t6 == selfkey) ? 6 : p;
  p = (t5 == selfkey) ? 5 : p;
  p = (t4 == selfkey) ? 4 : p;
  p = (t3 == selfkey) ? 3 : p;
  p = (t2 == selfkey) ? 2 : p;
  p = (t1 == selfkey) ? 1 : p;
  p = (t0 == selfkey) ? 0 : p;
  const int nb0 = (int)((p > 0 ? t0 : t1) & 511u);
  const int nb1 = (int)((p > 1 ? t1 : t2) & 511u);
  const int nb2 = (int)((p > 2 ? t2 : t3) & 511u);
  const int nb3 = (int)((p > 3 ? t3 : t4) & 511u);
  const int nb4 = (int)((p > 4 ? t4 : t5) & 511u);
  const int nb5 = (int)((p > 5 ? t5 : t6) & 511u);

  // ---------------- Phase C: agg1 = (self + 6 nbrs)/7 + b1, ReLU -> r_s (bf16)
  {
    float acc[HDIM];
#pragma unroll
    for (int o = 0; o < HDIM; ++o) acc[o] = 0.f;
    const int rows[7] = {tid, nb0, nb1, nb2, nb3, nb4, nb5};
#pragma unroll
    for (int r = 0; r < 7; ++r) {
      const unsigned* hp = reinterpret_cast<const unsigned*>(hbuf[rows[r]]);
      const uint4 ha = *reinterpret_cast<const uint4*>(hp);
      const uint4 hb = *reinterpret_cast<const uint4*>(hp + 4);
      const unsigned hd[8] = {ha.x, ha.y, ha.z, ha.w, hb.x, hb.y, hb.z, hb.w};
#pragma unroll
      for (int q = 0; q < 8; ++q) {
        acc[2 * q]     += bflo(hd[q]);
        acc[2 * q + 1] += bfhi(hd[q]);
      }
    }
    const float inv = 1.0f / 7.0f;
    unsigned* rp = reinterpret_cast<unsigned*>(r_s[tid]);
#pragma unroll
    for (int q = 0; q < 8; ++q) {
      const float v0 = fmaxf(acc[2 * q]     * inv + b1[2 * q],     0.f);
      const float v1 = fmaxf(acc[2 * q + 1] * inv + b1[2 * q + 1], 0.f);
      rp[q] = (unsigned)(unsigned short)f2bf(v0) |
              ((unsigned)(unsigned short)f2bf(v1) << 16);
    }
  }
  __syncthreads();

  // ---------------- Phase D: h2 = r @ W2 (K=16 zero-padded to 32) -> hbuf (f32)
  float* h2f = reinterpret_cast<float*>(hbuf);      // row stride 12 floats (48B)
  short8 bw2 = {0, 0, 0, 0, 0, 0, 0, 0};
  if (lkg < 2 && lcol < ODIM) {
#pragma unroll
    for (int e = 0; e < 8; ++e) {
      const int k = lkg * 8 + e;
      bw2[e] = f2bf(W2[k * ODIM + lcol]);
    }
  }
#pragma unroll
  for (int t = 0; t < 4; ++t) {
    const int nt = wv * 64 + t * 16;
    short8 af = {0, 0, 0, 0, 0, 0, 0, 0};
    if (lkg < 2) {
      af = *reinterpret_cast<const short8*>(&r_s[nt + lcol][lkg * 8]);
    }
    f32x4 acc = {0.f, 0.f, 0.f, 0.f};
    acc = __builtin_amdgcn_mfma_f32_16x16x32_bf16(af, bw2, acc, 0, 0, 0);
#pragma unroll
    for (int i = 0; i < 4; ++i) {
      if (lcol < ODIM) h2f[(nt + lkg * 4 + i) * 12 + lcol] = acc[i];
    }
  }
  __syncthreads();

  // ---------------- Phase E: agg2 = (self + 6 nbrs)/7 + b2 -> out (f32)
  {
    float acc[ODIM];
#pragma unroll
    for (int c = 0; c < ODIM; ++c) acc[c] = 0.f;
    const int rows[7] = {tid, nb0, nb1, nb2, nb3, nb4, nb5};
#pragma unroll
    for (int r = 0; r < 7; ++r) {
      const float* hp = h2f + rows[r] * 12;
#pragma unroll
      for (int c = 0; c < ODIM; ++c) acc[c] += hp[c];
    }
    const float inv = 1.0f / 7.0f;
    float* op = out + (size_t)(gbase + tid) * ODIM;
#pragma unroll
    for (int c = 0; c < ODIM; c += 2) {
      float2 v;
      v.x = acc[c]     * inv + b2[c];
      v.y = acc[c + 1] * inv + b2[c + 1];
      *reinterpret_cast<float2*>(op + c) = v;
    }
  }
}

extern "C" void kernel_launch(void* const* d_in, const int* in_sizes, int n_in,
                              void* d_out, int out_size, void* d_ws, size_t ws_size,
                              hipStream_t stream) {
  const int*   coo = (const int*)  d_in[0];
  const float* x   = (const float*)d_in[1];
  const float* W1  = (const float*)d_in[2];
  const float* b1  = (const float*)d_in[3];
  const float* W2  = (const float*)d_in[4];
  const float* b2  = (const float*)d_in[5];
  gnet_fused<<<dim3(512), dim3(512), 0, stream>>>(coo, x, W1, b1, W2, b2,
                                                  (float*)d_out);
}

// Round 5
// 34.126 us; speedup vs baseline: 2.5133x; 1.0051x over previous
//
#include <hip/hip_runtime.h>
#include <hip/hip_bf16.h>

#define NPE   512
#define F_IN  128
#define HDIM  16
#define ODIM  10

typedef __attribute__((ext_vector_type(8))) short short8;
typedef __attribute__((ext_vector_type(4))) float f32x4;

static __device__ __forceinline__ unsigned pkbf(float lo, float hi) {
  __hip_bfloat162 h = __float22bfloat162_rn(make_float2(lo, hi));
  unsigned r;
  __builtin_memcpy(&r, &h, 4);                     // v_cvt_pk_bf16_f32
  return r;
}
static __device__ __forceinline__ short f2bf(float f) {
  __hip_bfloat16 h = __float2bfloat16(f);
  short r;
  __builtin_memcpy(&r, &h, 2);
  return r;
}
static __device__ __forceinline__ float bflo(unsigned d) {
  return __builtin_bit_cast(float, d << 16);
}
static __device__ __forceinline__ float bfhi(unsigned d) {
  return __builtin_bit_cast(float, d & 0xffff0000u);
}
static __device__ __forceinline__ unsigned umin2(unsigned a, unsigned b) { return a < b ? a : b; }
static __device__ __forceinline__ unsigned umax2(unsigned a, unsigned b) { return a > b ? a : b; }

__global__ __launch_bounds__(512, 4) void gnet_fused(
    const int* __restrict__ coo, const float* __restrict__ x,
    const float* __restrict__ W1, const float* __restrict__ b1,
    const float* __restrict__ W2, const float* __restrict__ b2,
    float* __restrict__ out)
{
  __shared__ __align__(16) short    hbuf[NPE][24];  // h1 bf16, then h2 f32[12] alias
  __shared__ __align__(16) short    r_s [NPE][24];  // relu(agg1) bf16
  __shared__ unsigned short cellof_s[NPE];          // cell id per node
  __shared__ unsigned       cnt_s [256];
  __shared__ unsigned       scan_s[256];
  __shared__ unsigned       cur_s [256];
  __shared__ unsigned short bucket_s[NPE];
  __shared__ unsigned       top7_s[256][8];
  __shared__ unsigned       tile_c;
  __shared__ unsigned       sortflag;

  const int tid   = threadIdx.x;
  const int gbase = blockIdx.x * NPE;
  const int ln    = tid & 63;
  const int wv    = tid >> 6;
  const int lcol  = ln & 15;
  const int lkg   = ln >> 4;

  const int cx = coo[(gbase + tid) * 3 + 0];
  const int cy = coo[(gbase + tid) * 3 + 1];
  const int mycell = cy * 16 + cx;
  cellof_s[tid] = (unsigned short)mycell;
  if (tid == 0) { tile_c = 0; sortflag = 0; }
  __syncthreads();   // the ONLY barrier before the big join

  // W1 fragments (all waves; used in steal loop)
  short8 bw1[4];
#pragma unroll
  for (int s = 0; s < 4; ++s) {
#pragma unroll
    for (int e = 0; e < 8; ++e) {
      const int k = s * 32 + lkg * 8 + e;
      bw1[s][e] = f2bf(W1[k * HDIM + lcol]);
    }
  }

  // ---------------- wave 0: counting sort (lockstep, no block barriers)
  if (wv == 0) {
#pragma unroll
    for (int q = 0; q < 4; ++q) cnt_s[ln * 4 + q] = 0;
    __threadfence_block();
#pragma unroll
    for (int q = 0; q < 8; ++q)
      atomicAdd(&cnt_s[cellof_s[ln + q * 64]], 1u);
    __threadfence_block();
    const unsigned c0 = cnt_s[ln * 4 + 0], c1 = cnt_s[ln * 4 + 1];
    const unsigned c2 = cnt_s[ln * 4 + 2], c3 = cnt_s[ln * 4 + 3];
    const unsigned psum = c0 + c1 + c2 + c3;
    unsigned sv = psum;
#pragma unroll
    for (int off = 1; off < 64; off <<= 1) {
      unsigned u = __shfl_up(sv, off, 64);
      if (ln >= off) sv += u;
    }
    const unsigned basex = sv - psum;               // exclusive over lane groups
    const unsigned e0 = basex + c0, e1 = e0 + c1, e2 = e1 + c2, e3 = e2 + c3;
    scan_s[ln * 4 + 0] = e0; cur_s[ln * 4 + 0] = e0 - c0;
    scan_s[ln * 4 + 1] = e1; cur_s[ln * 4 + 1] = e1 - c1;
    scan_s[ln * 4 + 2] = e2; cur_s[ln * 4 + 2] = e2 - c2;
    scan_s[ln * 4 + 3] = e3; cur_s[ln * 4 + 3] = e3 - c3;
    __threadfence_block();
#pragma unroll
    for (int q = 0; q < 8; ++q) {
      const int node = ln + q * 64;
      const unsigned slot = atomicAdd(&cur_s[cellof_s[node]], 1u);
      bucket_s[slot] = (unsigned short)node;
    }
    __threadfence_block();
    if (ln == 0) *(volatile unsigned*)&sortflag = 1u;
  } else if (wv < 4) {
    while (*(volatile unsigned*)&sortflag == 0u) __builtin_amdgcn_s_sleep(8);
    __threadfence_block();
  }

  // ---------------- waves 0-3: cell-level knn (one cell per thread)
  if (wv < 4 && cnt_s[tid] != 0) {
    const int ccx = tid & 15, ccy = tid >> 4;
    unsigned k0 = 0x7fffffffu, k1 = k0, k2 = k0, k3 = k0, k4 = k0, k5 = k0, k6 = k0;
    auto insert7 = [&](unsigned key) {
      if (key < k6) {
        k6 = key;
        unsigned lo, hi;
        lo = umin2(k5, k6); hi = umax2(k5, k6); k5 = lo; k6 = hi;
        lo = umin2(k4, k5); hi = umax2(k4, k5); k4 = lo; k5 = hi;
        lo = umin2(k3, k4); hi = umax2(k3, k4); k3 = lo; k4 = hi;
        lo = umin2(k2, k3); hi = umax2(k2, k3); k2 = lo; k3 = hi;
        lo = umin2(k1, k2); hi = umax2(k1, k2); k1 = lo; k2 = hi;
        lo = umin2(k0, k1); hi = umax2(k0, k1); k0 = lo; k1 = hi;
      }
    };
    auto scan_cell = [&](int c, unsigned kb) {
      const unsigned e = scan_s[c];
      const unsigned n = cnt_s[c];
      for (unsigned q = e - n; q < e; ++q) insert7(kb | (unsigned)bucket_s[q]);
    };
    scan_cell(tid, 0u);
    for (int r = 1; r <= 15; ++r) {
      const unsigned r2 = (unsigned)(r * r);
      if (r2 > (k6 >> 9)) break;
      for (int sg = 0; sg < 2; ++sg) {              // rows dy = ±r
        const int yy = ccy + (sg ? r : -r);
        if (yy < 0 || yy > 15) continue;
        const int xlo = ccx - r < 0 ? 0 : ccx - r;
        const int xhi = ccx + r > 15 ? 15 : ccx + r;
        for (int xx = xlo; xx <= xhi; ++xx) {
          const int dx = xx - ccx;
          const unsigned kb = (unsigned)(dx * dx + (int)r2) << 9;
          if (kb < k6) scan_cell(yy * 16 + xx, kb);
        }
      }
      for (int sg = 0; sg < 2; ++sg) {              // cols dx = ±r
        const int xx = ccx + (sg ? r : -r);
        if (xx < 0 || xx > 15) continue;
        const int ylo = ccy - r + 1 < 0 ? 0 : ccy - r + 1;
        const int yhi = ccy + r - 1 > 15 ? 15 : ccy + r - 1;
        for (int yy = ylo; yy <= yhi; ++yy) {
          const int dy = yy - ccy;
          const unsigned kb = (unsigned)(dy * dy + (int)r2) << 9;
          if (kb < k6) scan_cell(yy * 16 + xx, kb);
        }
      }
    }
    unsigned* tp = top7_s[tid];
    tp[0] = k0; tp[1] = k1; tp[2] = k2; tp[3] = k3; tp[4] = k4; tp[5] = k5; tp[6] = k6;
  }

  // ---------------- gemm1 steal loop: 16 batches x 32 rows, 16 loads in flight
  for (;;) {
    int t = 0;
    if (ln == 0) t = (int)atomicAdd(&tile_c, 1u);
    t = __shfl(t, 0, 64);
    if (t >= 16) break;
    const int base = t * 32;
    const float4* pA = reinterpret_cast<const float4*>(
        x + (size_t)(gbase + base + lcol) * F_IN + lkg * 8);
    const float4* pB = reinterpret_cast<const float4*>(
        x + (size_t)(gbase + base + 16 + lcol) * F_IN + lkg * 8);
    float4 a0 = pA[0],  a1 = pA[1],  a2 = pA[8],  a3 = pA[9];
    float4 a4 = pA[16], a5 = pA[17], a6 = pA[24], a7 = pA[25];
    float4 b0 = pB[0],  b1v = pB[1], b2v = pB[8], b3 = pB[9];
    float4 b4 = pB[16], b5 = pB[17], b6 = pB[24], b7 = pB[25];

    f32x4 accA = {0.f, 0.f, 0.f, 0.f};
    f32x4 accB = {0.f, 0.f, 0.f, 0.f};
    const float4 av[8] = {a0, a1, a2, a3, a4, a5, a6, a7};
    const float4 bv[8] = {b0, b1v, b2v, b3, b4, b5, b6, b7};
#pragma unroll
    for (int s = 0; s < 4; ++s) {
      const float4 u = av[2 * s], v = av[2 * s + 1];
      uint4 pk = {pkbf(u.x, u.y), pkbf(u.z, u.w), pkbf(v.x, v.y), pkbf(v.z, v.w)};
      short8 af = __builtin_bit_cast(short8, pk);
      accA = __builtin_amdgcn_mfma_f32_16x16x32_bf16(af, bw1[s], accA, 0, 0, 0);
    }
#pragma unroll
    for (int s = 0; s < 4; ++s) {
      const float4 u = bv[2 * s], v = bv[2 * s + 1];
      uint4 pk = {pkbf(u.x, u.y), pkbf(u.z, u.w), pkbf(v.x, v.y), pkbf(v.z, v.w)};
      short8 bf = __builtin_bit_cast(short8, pk);
      accB = __builtin_amdgcn_mfma_f32_16x16x32_bf16(bf, bw1[s], accB, 0, 0, 0);
    }
#pragma unroll
    for (int i = 0; i < 4; ++i) {
      hbuf[base + lkg * 4 + i][lcol]      = f2bf(accA[i]);
      hbuf[base + 16 + lkg * 4 + i][lcol] = f2bf(accB[i]);
    }
  }
  __syncthreads();   // join: hbuf + top7_s complete

  // ---------------- per-node neighbors from cell top-7 (branch-free self skip)
  const unsigned* tp = top7_s[mycell];
  const unsigned t0 = tp[0], t1 = tp[1], t2 = tp[2], t3 = tp[3];
  const unsigned t4 = tp[4], t5 = tp[5], t6 = tp[6];
  const unsigned selfkey = (unsigned)tid;
  int p = 7;
  p = (t6 == selfkey) ? 6 : p;
  p = (t5 == selfkey) ? 5 : p;
  p = (t4 == selfkey) ? 4 : p;
  p = (t3 == selfkey) ? 3 : p;
  p = (t2 == selfkey) ? 2 : p;
  p = (t1 == selfkey) ? 1 : p;
  p = (t0 == selfkey) ? 0 : p;
  const int nb0 = (int)((p > 0 ? t0 : t1) & 511u);
  const int nb1 = (int)((p > 1 ? t1 : t2) & 511u);
  const int nb2 = (int)((p > 2 ? t2 : t3) & 511u);
  const int nb3 = (int)((p > 3 ? t3 : t4) & 511u);
  const int nb4 = (int)((p > 4 ? t4 : t5) & 511u);
  const int nb5 = (int)((p > 5 ? t5 : t6) & 511u);

  // ---------------- Phase C: agg1 = (self + 6 nbrs)/7 + b1, ReLU -> r_s (bf16)
  {
    float acc[HDIM];
#pragma unroll
    for (int o = 0; o < HDIM; ++o) acc[o] = 0.f;
    const int rows[7] = {tid, nb0, nb1, nb2, nb3, nb4, nb5};
#pragma unroll
    for (int r = 0; r < 7; ++r) {
      const unsigned* hp = reinterpret_cast<const unsigned*>(hbuf[rows[r]]);
      const uint4 ha = *reinterpret_cast<const uint4*>(hp);
      const uint4 hb = *reinterpret_cast<const uint4*>(hp + 4);
      const unsigned hd[8] = {ha.x, ha.y, ha.z, ha.w, hb.x, hb.y, hb.z, hb.w};
#pragma unroll
      for (int q = 0; q < 8; ++q) {
        acc[2 * q]     += bflo(hd[q]);
        acc[2 * q + 1] += bfhi(hd[q]);
      }
    }
    const float inv = 1.0f / 7.0f;
    unsigned* rp = reinterpret_cast<unsigned*>(r_s[tid]);
#pragma unroll
    for (int q = 0; q < 8; ++q) {
      const float v0 = fmaxf(acc[2 * q]     * inv + b1[2 * q],     0.f);
      const float v1 = fmaxf(acc[2 * q + 1] * inv + b1[2 * q + 1], 0.f);
      rp[q] = pkbf(v0, v1);
    }
  }
  __syncthreads();

  // ---------------- Phase D: h2 = r @ W2 (K=16 zero-padded to 32) -> hbuf (f32)
  float* h2f = reinterpret_cast<float*>(hbuf);      // row stride 12 floats (48 B)
  short8 bw2 = {0, 0, 0, 0, 0, 0, 0, 0};
  if (lkg < 2 && lcol < ODIM) {
#pragma unroll
    for (int e = 0; e < 8; ++e) {
      const int k = lkg * 8 + e;
      bw2[e] = f2bf(W2[k * ODIM + lcol]);
    }
  }
#pragma unroll
  for (int t = 0; t < 4; ++t) {
    const int nt = wv * 64 + t * 16;
    short8 af = {0, 0, 0, 0, 0, 0, 0, 0};
    if (lkg < 2) {
      af = *reinterpret_cast<const short8*>(&r_s[nt + lcol][lkg * 8]);
    }
    f32x4 acc = {0.f, 0.f, 0.f, 0.f};
    acc = __builtin_amdgcn_mfma_f32_16x16x32_bf16(af, bw2, acc, 0, 0, 0);
#pragma unroll
    for (int i = 0; i < 4; ++i) {
      if (lcol < ODIM) h2f[(nt + lkg * 4 + i) * 12 + lcol] = acc[i];
    }
  }
  __syncthreads();

  // ---------------- Phase E: agg2 = (self + 6 nbrs)/7 + b2 -> out (f32)
  {
    f32x4 s0 = {0.f, 0.f, 0.f, 0.f}, s1 = s0, s2 = s0;
    const int rows[7] = {tid, nb0, nb1, nb2, nb3, nb4, nb5};
#pragma unroll
    for (int r = 0; r < 7; ++r) {
      const f32x4* hp = reinterpret_cast<const f32x4*>(h2f + rows[r] * 12);
      s0 += hp[0]; s1 += hp[1]; s2 += hp[2];
    }
    const float inv = 1.0f / 7.0f;
    float acc[12];
#pragma unroll
    for (int c = 0; c < 4; ++c) { acc[c] = s0[c]; acc[4 + c] = s1[c]; acc[8 + c] = s2[c]; }
    float* op = out + (size_t)(gbase + tid) * ODIM;
#pragma unroll
    for (int c = 0; c < ODIM; c += 2) {
      float2 v;
      v.x = acc[c]     * inv + b2[c];
      v.y = acc[c + 1] * inv + b2[c + 1];
      *reinterpret_cast<float2*>(op + c) = v;
    }
  }
}

extern "C" void kernel_launch(void* const* d_in, const int* in_sizes, int n_in,
                              void* d_out, int out_size, void* d_ws, size_t ws_size,
                              hipStream_t stream) {
  const int*   coo = (const int*)  d_in[0];
  const float* x   = (const float*)d_in[1];
  const float* W1  = (const float*)d_in[2];
  const float* b1  = (const float*)d_in[3];
  const float* W2  = (const float*)d_in[4];
  const float* b2  = (const float*)d_in[5];
  gnet_fused<<<dim3(512), dim3(512), 0, stream>>>(coo, x, W1, b1, W2, b2,
                                                  (float*)d_out);
}